// Round 7
// baseline (63.079 us; speedup 1.0000x reference)
//
#include <hip/hip_runtime.h>
#include <math.h>

namespace {

constexpr int Bn = 2, Hn = 128, Wn = 128, Cn = 256, Vn = 64;

__device__ __forceinline__ void load8(float* r, const float* p) {
    float4 a = *(const float4*)(p);
    float4 b = *(const float4*)(p + 4);
    r[0]=a.x; r[1]=a.y; r[2]=a.z; r[3]=a.w;
    r[4]=b.x; r[5]=b.y; r[6]=b.z; r[7]=b.w;
}

// 256 thr = 16 pixels x 16 channel-splits, 1 pixel/lane (R4 skeleton: 72
// VGPR, 8192 waves). New in R6:
//  (1) XCD-chunked swizzle: hw round-robins blockIdx across 8 XCDs; remap
//      (bid&7)*256 + bid>>3 so each XCD owns a contiguous 32-row h-band ->
//      same-XCD blocks share 4/5 ref rows in their L2 (R5 showed scattered
//      blocks tripled TCC fetch).
//  (2) OOB-row shortcut: padded rows contribute exactly score 0 / value 0;
//      replace 30 vmem + 120 FMA with a 6-VALU exact softmax update.
//  (3) Interior fast path: only 2 waves per h-row have OOB columns; interior
//      lanes skip r-zeroing and predication entirely.
__global__ __launch_bounds__(256)
void local_attn_kernel(const float* __restrict__ mainp,
                       const float* __restrict__ mainv,
                       const float* __restrict__ refp,
                       const float* __restrict__ refv,
                       float* __restrict__ outp)
{
    const int t = threadIdx.x;
    const int s = t & 15;       // channel/value split 0..15
    const int p = t >> 4;       // pixel 0..15

    const int bid = blockIdx.x;               // 0..2047
    const int wid = (bid & 7) * 256 + (bid >> 3);   // XCD-chunked work id
    const int seg = wid & 7;
    const int h   = (wid >> 3) & (Hn - 1);
    const int b   = wid >> 10;
    const int w   = seg * 16 + p;
    const int rowbase = b * Hn + h;
    const bool colok = (w >= 2) && (w <= Wn - 3);   // all 5 cols in-bounds

    // this lane's 16 main channels: s*8..s*8+7 and 128+s*8..128+s*8+7
    float m[16];
    const float* mp = mainp + ((size_t)rowbase * Wn + w) * Cn + s * 8;
    load8(m,     mp);
    load8(m + 8, mp + 128);

    // self score (slot 25): full dot via 4-step shuffle reduce over s bits
    float self = 0.f;
    #pragma unroll
    for (int c = 0; c < 16; ++c) self = fmaf(m[c], m[c], self);
    self += __shfl_xor(self, 1);
    self += __shfl_xor(self, 2);
    self += __shfl_xor(self, 4);
    self += __shfl_xor(self, 8);

    // online-softmax state seeded with the self slot (weight exp(0)=1)
    float mx = self, den = 1.f;
    float acc[4];
    {
        const float* mvp = mainv + ((size_t)rowbase * Wn + w) * Vn + s * 4;
        float4 a = *(const float4*)(mvp);
        acc[0]=a.x; acc[1]=a.y; acc[2]=a.z; acc[3]=a.w;
    }

    #pragma unroll 1
    for (int di = 0; di < 5; ++di) {
        const int hh = h + di - 2;
        if ((unsigned)hh >= (unsigned)Hn) {
            // padded row: 5 slots of score exactly 0, values exactly 0.
            const float nm = fmaxf(mx, 0.f);
            const float e  = __expf(mx - nm);
            den = den * e + 5.f * __expf(0.f - nm);
            #pragma unroll
            for (int c = 0; c < 4; ++c) acc[c] *= e;
            mx = nm;
            continue;
        }
        const size_t rbase = (size_t)(b * Hn + hh) * Wn;
        const float* rp = refp + rbase * Cn + s * 8;

        float sc[5];
        if (colok) {
            // ---- fast path: unconditional loads, no zeroing
            #pragma unroll
            for (int dj = 0; dj < 5; ++dj) {
                float r[8];
                load8(r, rp + (size_t)(w - 2 + dj) * Cn);
                float a = 0.f;
                #pragma unroll
                for (int c = 0; c < 8; ++c) a = fmaf(m[c], r[c], a);
                sc[dj] = a;
            }
            #pragma unroll
            for (int dj = 0; dj < 5; ++dj) {
                float r[8];
                load8(r, rp + (size_t)(w - 2 + dj) * Cn + 128);
                float a = sc[dj];
                #pragma unroll
                for (int c = 0; c < 8; ++c) a = fmaf(m[8 + c], r[c], a);
                sc[dj] = a;
            }
        } else {
            // ---- edge path: predicated (only 2 waves per h-row land here)
            #pragma unroll
            for (int dj = 0; dj < 5; ++dj) {
                const int col = w - 2 + dj;
                const bool ok = (unsigned)col < (unsigned)Wn;
                float r[8];
                #pragma unroll
                for (int c = 0; c < 8; ++c) r[c] = 0.f;
                if (ok) load8(r, rp + (size_t)col * Cn);
                float a = 0.f;
                #pragma unroll
                for (int c = 0; c < 8; ++c) a = fmaf(m[c], r[c], a);
                sc[dj] = a;
            }
            #pragma unroll
            for (int dj = 0; dj < 5; ++dj) {
                const int col = w - 2 + dj;
                const bool ok = (unsigned)col < (unsigned)Wn;
                float r[8];
                #pragma unroll
                for (int c = 0; c < 8; ++c) r[c] = 0.f;
                if (ok) load8(r, rp + (size_t)col * Cn + 128);
                float a = sc[dj];
                #pragma unroll
                for (int c = 0; c < 8; ++c) a = fmaf(m[8 + c], r[c], a);
                sc[dj] = a;
            }
        }

        // reduce partial dots across the 16 split lanes (lane bits 0..3)
        #pragma unroll
        for (int k = 0; k < 5; ++k) {
            float v = sc[k];
            v += __shfl_xor(v, 1);
            v += __shfl_xor(v, 2);
            v += __shfl_xor(v, 4);
            v += __shfl_xor(v, 8);
            sc[k] = v;
        }

        // ---- online softmax row update
        const float rm = fmaxf(fmaxf(fmaxf(sc[0], sc[1]), fmaxf(sc[2], sc[3])), sc[4]);
        const float nm = fmaxf(mx, rm);
        const float e  = __expf(mx - nm);
        float wk[5];
        float sum = 0.f;
        #pragma unroll
        for (int k = 0; k < 5; ++k) { wk[k] = __expf(sc[k] - nm); sum += wk[k]; }
        den = den * e + sum;
        #pragma unroll
        for (int c = 0; c < 4; ++c) acc[c] *= e;
        mx = nm;

        // ---- fused value row (lane owns V channels s*4 .. s*4+3)
        const float* rvp = refv + rbase * Vn + s * 4;
        if (colok) {
            #pragma unroll
            for (int dj = 0; dj < 5; ++dj) {
                float4 rv = *(const float4*)(rvp + (size_t)(w - 2 + dj) * Vn);
                const float wkj = wk[dj];
                acc[0] = fmaf(wkj, rv.x, acc[0]);
                acc[1] = fmaf(wkj, rv.y, acc[1]);
                acc[2] = fmaf(wkj, rv.z, acc[2]);
                acc[3] = fmaf(wkj, rv.w, acc[3]);
            }
        } else {
            #pragma unroll
            for (int dj = 0; dj < 5; ++dj) {
                const int col = w - 2 + dj;
                float4 rv = make_float4(0.f, 0.f, 0.f, 0.f);
                if ((unsigned)col < (unsigned)Wn)
                    rv = *(const float4*)(rvp + (size_t)col * Vn);
                const float wkj = wk[dj];
                acc[0] = fmaf(wkj, rv.x, acc[0]);
                acc[1] = fmaf(wkj, rv.y, acc[1]);
                acc[2] = fmaf(wkj, rv.z, acc[2]);
                acc[3] = fmaf(wkj, rv.w, acc[3]);
            }
        }
    }

    const float inv = 1.f / den;
    float* op = outp + ((size_t)rowbase * Wn + w) * Vn + s * 4;
    float4 o;
    o.x = acc[0]*inv; o.y = acc[1]*inv; o.z = acc[2]*inv; o.w = acc[3]*inv;
    *(float4*)op = o;
}

} // namespace

extern "C" void kernel_launch(void* const* d_in, const int* in_sizes, int n_in,
                              void* d_out, int out_size, void* d_ws, size_t ws_size,
                              hipStream_t stream)
{
    const float* mainp = (const float*)d_in[0];
    const float* mainv = (const float*)d_in[1];
    const float* refp  = (const float*)d_in[2];
    const float* refv  = (const float*)d_in[3];
    float* outp = (float*)d_out;

    dim3 grid(Bn * Hn * 8);   // 2048 blocks; swizzled to XCD-contiguous h-bands
    dim3 block(256);          // 16 pixels x 16 splits
    hipLaunchKernelGGL(local_attn_kernel, grid, block, 0, stream,
                       mainp, mainv, refp, refv, outp);
}